// Round 1
// baseline (296.815 us; speedup 1.0000x reference)
//
#include <hip/hip_runtime.h>
#include <hip/hip_bf16.h>

// Problem constants
#define N_TOK   16384      // B*T
#define HDIM    2048       // H*d_h
#define NH      16
#define DH      128
#define NPAIRS  120
#define KCHUNKS 8
#define NKT     (N_TOK / 64)            // 256 k-tiles of 64 tokens
#define KT_PER_CHUNK (NKT / KCHUNKS)    // 32
#define PANEL_BYTES 8192                // 128 c-rows x 64 tokens x 1B (fp8)

// Workspace layout (bytes) — total ~41.5 MB
#define SUM_OFF    0u
#define SUMSQ_OFF  8192u
#define MU_OFF     16384u
#define RINV_OFF   24576u
#define PC_OFF     36864u                     // 120*128*128 f32 = 7,864,320 B
#define XT_OFF     7901184u                   // 2048*16384 fp8 = 33,554,432 B

typedef float     f32x4 __attribute__((ext_vector_type(4)));
typedef long long i64t;

// ---------------------------------------------------------------- fp8 e4m3 pack
#if __has_builtin(__builtin_amdgcn_cvt_pk_fp8_f32)
__device__ __forceinline__ unsigned pk4_fp8(float a, float b, float c, float d) {
    int w = __builtin_amdgcn_cvt_pk_fp8_f32(a, b, 0, false);   // bytes 0,1
    w = __builtin_amdgcn_cvt_pk_fp8_f32(c, d, w, true);        // bytes 2,3
    return (unsigned)w;
}
#else
__device__ __forceinline__ unsigned char f2e4m3_sw(float f) {
    unsigned u = __float_as_uint(f);
    unsigned s = (u >> 24) & 0x80u;
    unsigned a = u & 0x7fffffffu;
    if (a >= 0x43e00000u) return (unsigned char)(s | 0x7eu);   // clamp to 448
    if (a < 0x3c800000u) {                                     // |x| < 2^-6: subnormal
        float av = __uint_as_float(a);
        int q = (int)rintf(av * 512.0f);                       // units of 2^-9
        return (unsigned char)(s | (unsigned)q);               // q==8 -> 0x08 == 2^-6 normal
    }
    unsigned lsb = (a >> 20) & 1u;
    a += 0x7ffffu + lsb;                                       // RNE to 3 mantissa bits
    int e8 = (int)(a >> 23) - 120;                             // -127 + 7
    unsigned m = (a >> 20) & 7u;
    return (unsigned char)(s | ((unsigned)e8 << 3) | m);
}
__device__ __forceinline__ unsigned pk4_fp8(float a, float b, float c, float d) {
    return (unsigned)f2e4m3_sw(a) | ((unsigned)f2e4m3_sw(b) << 8) |
           ((unsigned)f2e4m3_sw(c) << 16) | ((unsigned)f2e4m3_sw(d) << 24);
}
#endif

// ---------------------------------------------------------------- pass 1: fused stats + panelized transpose + fp8
// Block = one 8 KB panel: head h, tokens n0..n0+63, all 128 head-dims.
__global__ __launch_bounds__(256)
void stats_transpose_kernel(const float* __restrict__ X,
                            float* __restrict__ sum, float* __restrict__ sumsq,
                            unsigned char* __restrict__ Xt) {
    __shared__ float tile[64][129];               // stride 129
    __shared__ float sred[4][32][8];              // cross-wave stats partials
    const int h  = blockIdx.x;                    // 0..15
    const int by = blockIdx.y;                    // 0..255
    const int n0 = by * 64;
    const int tx = threadIdx.x;
    const int w  = tx >> 6, l = tx & 63;
    const int cq = tx & 31;                       // float4 index within 128-col slice
    const int rq0 = tx >> 5;                      // 0..7

    float4 s  = make_float4(0.f, 0.f, 0.f, 0.f);
    float4 ss = make_float4(0.f, 0.f, 0.f, 0.f);
    #pragma unroll
    for (int it = 0; it < 8; ++it) {
        int r = it * 8 + rq0;
        float4 x = *(const float4*)(X + (size_t)(n0 + r) * HDIM + h * DH + cq * 4);
        s.x += x.x; s.y += x.y; s.z += x.z; s.w += x.w;
        ss.x += x.x * x.x; ss.y += x.y * x.y; ss.z += x.z * x.z; ss.w += x.w * x.w;
        tile[r][cq * 4 + 0] = x.x; tile[r][cq * 4 + 1] = x.y;
        tile[r][cq * 4 + 2] = x.z; tile[r][cq * 4 + 3] = x.w;
    }
    s.x += __shfl_down(s.x, 32);  s.y += __shfl_down(s.y, 32);
    s.z += __shfl_down(s.z, 32);  s.w += __shfl_down(s.w, 32);
    ss.x += __shfl_down(ss.x, 32); ss.y += __shfl_down(ss.y, 32);
    ss.z += __shfl_down(ss.z, 32); ss.w += __shfl_down(ss.w, 32);
    if (l < 32) {
        sred[w][l][0] = s.x;  sred[w][l][1] = s.y;
        sred[w][l][2] = s.z;  sred[w][l][3] = s.w;
        sred[w][l][4] = ss.x; sred[w][l][5] = ss.y;
        sred[w][l][6] = ss.z; sred[w][l][7] = ss.w;
    }
    __syncthreads();
    if (tx < 32) {                                // wave 0 finishes stats
        float a0 = 0.f, a1 = 0.f, a2 = 0.f, a3 = 0.f;
        float b0 = 0.f, b1 = 0.f, b2 = 0.f, b3 = 0.f;
        #pragma unroll
        for (int w2 = 0; w2 < 4; ++w2) {
            a0 += sred[w2][tx][0]; a1 += sred[w2][tx][1];
            a2 += sred[w2][tx][2]; a3 += sred[w2][tx][3];
            b0 += sred[w2][tx][4]; b1 += sred[w2][tx][5];
            b2 += sred[w2][tx][6]; b3 += sred[w2][tx][7];
        }
        int c = h * DH + tx * 4;
        atomicAdd(&sum[c + 0], a0);  atomicAdd(&sum[c + 1], a1);
        atomicAdd(&sum[c + 2], a2);  atomicAdd(&sum[c + 3], a3);
        atomicAdd(&sumsq[c + 0], b0); atomicAdd(&sumsq[c + 1], b1);
        atomicAdd(&sumsq[c + 2], b2); atomicAdd(&sumsq[c + 3], b3);
    }
    // transpose write: 512 16B-chunks (one panel), contiguous per wave-instruction
    unsigned char* panel = Xt + ((size_t)h * NKT + by) * PANEL_BYTES;
    #pragma unroll
    for (int it = 0; it < 2; ++it) {
        int q = it * 256 + tx;
        int c = q >> 2, o = q & 3;                // chunk = (dim c, tokens 16o..16o+15)
        uint4 pk;
        pk.x = pk4_fp8(tile[o*16+ 0][c], tile[o*16+ 1][c], tile[o*16+ 2][c], tile[o*16+ 3][c]);
        pk.y = pk4_fp8(tile[o*16+ 4][c], tile[o*16+ 5][c], tile[o*16+ 6][c], tile[o*16+ 7][c]);
        pk.z = pk4_fp8(tile[o*16+ 8][c], tile[o*16+ 9][c], tile[o*16+10][c], tile[o*16+11][c]);
        pk.w = pk4_fp8(tile[o*16+12][c], tile[o*16+13][c], tile[o*16+14][c], tile[o*16+15][c]);
        *(uint4*)(panel + c * 64 + o * 16) = pk;
    }
}

// ---------------------------------------------------------------- pass 2: mu / rinv
__global__ void finalize_kernel(const float* __restrict__ sum, const float* __restrict__ sumsq,
                                float* __restrict__ mu, float* __restrict__ rinv) {
    int c = blockIdx.x * 256 + threadIdx.x;       // grid 8 x 256 = 2048
    float m = sum[c] * (1.f / (float)N_TOK);
    float var = (sumsq[c] - (float)N_TOK * m * m) * (1.f / (float)(N_TOK - 1));
    var = fmaxf(var, 0.f);
    mu[c]   = m;
    rinv[c] = 1.f / (sqrtf(var) + 1e-8f);
}

// ---------------------------------------------------------------- pass 3: pairwise raw Gram via fp8 MFMA
// 2-phase double-buffered pipeline (catalog T3-lite "minimum 2-phase" template):
//   iter t: issue STAGE(buf^1, t+1) -> ds_read+MFMA on buf -> vmcnt(0)+lgkmcnt(0)+s_barrier
// No __syncthreads() in the loop => no forced drain before compute; prefetched load
// latency hides under the MFMA phase. One barrier per k-tile instead of two.
__device__ __forceinline__ void gload16(const void* gsrc, void* ldst) {
    __builtin_amdgcn_global_load_lds(
        (const __attribute__((address_space(1))) unsigned int*)gsrc,
        (__attribute__((address_space(3))) unsigned int*)ldst,
        16, 0, 0);
}

__global__ __launch_bounds__(256, 4)
void gram_kernel(const unsigned char* __restrict__ Xt, float* __restrict__ pairC) {
    const int kc = blockIdx.x;                    // K-chunk 0..7 -> XCD kc (linear%8)
    const int p  = blockIdx.y;                    // pair 0..119
    int i = 0, rem = p;
    while (rem >= NH - 1 - i) { rem -= NH - 1 - i; ++i; }
    const int j = i + 1 + rem;

    // [buf][A|B][8192] double-buffered staging: 32 KB -> still 4 blocks/CU (128 KB LDS)
    __shared__ alignas(16) unsigned char lds[2 * 2 * PANEL_BYTES];

    const int tx = threadIdx.x;
    const int w  = tx >> 6, l = tx & 63;
    const int wm = w >> 1, wn = w & 1;            // 2x2 wave grid over 128x128
    const int l15 = l & 15, quad = l >> 4;

    // Staging: panel = 128 rows x 4 chunks of 16B; chunk swizzle cc = cl ^ ((r>>1)&3)
    // (keeps 16B chunks intact; equals 8B-unit swizzle u' = u ^ (r&6))
    unsigned int goff0, goff1;
    {
        int r0 = tx >> 2, cl0 = tx & 3;
        goff0 = (unsigned int)(r0 * 64 + (cl0 ^ ((r0 >> 1) & 3)) * 16);
        int cfl = 256 + tx;
        int r1 = cfl >> 2, cl1 = cfl & 3;
        goff1 = (unsigned int)(r1 * 64 + (cl1 ^ ((r1 >> 1) & 3)) * 16);
    }
    const int lo0 = w * 1024;                     // wave-uniform LDS base, issue 0
    const int lo1 = 4096 + w * 1024;              // issue 1
    const char* Abase = (const char*)Xt + ((size_t)i * NKT + (size_t)kc * KT_PER_CHUNK) * PANEL_BYTES;
    const char* Bbase = (const char*)Xt + ((size_t)j * NKT + (size_t)kc * KT_PER_CHUNK) * PANEL_BYTES;

    f32x4 acc[4][4];
    #pragma unroll
    for (int mi = 0; mi < 4; ++mi)
        #pragma unroll
        for (int ni = 0; ni < 4; ++ni)
            acc[mi][ni] = (f32x4){0.f, 0.f, 0.f, 0.f};

    const int usw = l15 & 6;                      // row-dependent unit swizzle (rows within
                                                  // a frag read differ by 16 -> r&6 == l15&6)

    // ---- prologue: stage tile 0 into buf 0, drain, barrier
    {
        const char* pa = Abase;
        const char* pb = Bbase;
        char* base = (char*)lds;
        gload16(pa + goff0, base + lo0);
        gload16(pa + goff1, base + lo1);
        gload16(pb + goff0, base + 8192 + lo0);
        gload16(pb + goff1, base + 8192 + lo1);
    }
    asm volatile("s_waitcnt vmcnt(0)\n\ts_barrier" ::: "memory");

    int cur = 0;
    for (int kt = 0; kt < KT_PER_CHUNK; ++kt) {
        // ---- issue next tile's loads into the other buffer (prefetch)
        if (kt + 1 < KT_PER_CHUNK) {
            const char* pa = Abase + (size_t)(kt + 1) * PANEL_BYTES;
            const char* pb = Bbase + (size_t)(kt + 1) * PANEL_BYTES;
            char* base = (char*)lds + (cur ^ 1) * (2 * PANEL_BYTES);
            gload16(pa + goff0, base + lo0);
            gload16(pa + goff1, base + lo1);
            gload16(pb + goff0, base + 8192 + lo0);
            gload16(pb + goff1, base + 8192 + lo1);
        }

        // ---- compute current buffer
        const unsigned char* la = lds + cur * (2 * PANEL_BYTES);
        const unsigned char* lb = la + PANEL_BYTES;
        #pragma unroll
        for (int kh = 0; kh < 2; ++kh) {          // two K=32 fp8 MFMA steps per 64-token tile
            const int u = (kh * 4 + quad) ^ usw;  // swizzled 8B unit
            i64t a[4], b[4];
            #pragma unroll
            for (int mi = 0; mi < 4; ++mi) {
                int r = wm * 64 + mi * 16 + l15;
                a[mi] = *(const i64t*)(la + r * 64 + u * 8);
            }
            #pragma unroll
            for (int ni = 0; ni < 4; ++ni) {
                int r = wn * 64 + ni * 16 + l15;
                b[ni] = *(const i64t*)(lb + r * 64 + u * 8);
            }
            #pragma unroll
            for (int mi = 0; mi < 4; ++mi)
                #pragma unroll
                for (int ni = 0; ni < 4; ++ni)
                    acc[mi][ni] = __builtin_amdgcn_mfma_f32_16x16x32_fp8_fp8(
                        a[mi], b[ni], acc[mi][ni], 0, 0, 0);
        }

        // ---- end-of-iter: wait prefetched loads (latency covered by MFMA above),
        //      ensure our LDS reads retired, then one barrier. No __syncthreads drain.
        if (kt + 1 < KT_PER_CHUNK) {
            asm volatile("s_waitcnt vmcnt(0) lgkmcnt(0)\n\ts_barrier" ::: "memory");
        }
        cur ^= 1;
    }

    // Epilogue: partial raw Gram -> atomic accumulate (KCHUNKS contenders/address)
    float* pc = pairC + (size_t)p * (DH * DH);
    #pragma unroll
    for (int mi = 0; mi < 4; ++mi)
        #pragma unroll
        for (int ni = 0; ni < 4; ++ni)
            #pragma unroll
            for (int r = 0; r < 4; ++r) {
                int row = wm * 64 + mi * 16 + quad * 4 + r;  // d (head-i dim)
                int col = wn * 64 + ni * 16 + l15;           // e (head-j dim)
                atomicAdd(&pc[row * DH + col], acc[mi][ni][r]);
            }
}

// ---------------------------------------------------------------- pass 4: per-pair loss + final accumulate
__global__ void pair_reduce_kernel(const float* __restrict__ pairC, const float* __restrict__ G,
                                   const float* __restrict__ mu, const float* __restrict__ rinv,
                                   float* __restrict__ out) {
    int p = blockIdx.x;
    int i = 0, rem = p;
    while (rem >= NH - 1 - i) { rem -= NH - 1 - i; ++i; }
    int j = i + 1 + rem;
    __shared__ float smui[DH], smuj[DH], sri[DH], srj[DH];
    if (threadIdx.x < DH) {
        smui[threadIdx.x] = mu[i * DH + threadIdx.x];
        smuj[threadIdx.x] = mu[j * DH + threadIdx.x];
        sri[threadIdx.x]  = rinv[i * DH + threadIdx.x];
        srj[threadIdx.x]  = rinv[j * DH + threadIdx.x];
    }
    __syncthreads();
    const float invN = 1.f / (float)N_TOK;
    const float* pc = pairC + (size_t)p * (DH * DH);
    float s = 0.f;
    for (int idx = threadIdx.x; idx < DH * DH; idx += 256) {
        int d = idx >> 7, e = idx & 127;
        float cn = (pc[idx] * invN - smui[d] * smuj[e]) * sri[d] * srj[e];
        float diff = cn - ((d == e) ? 1.f : 0.f);
        s += diff * diff;
    }
    for (int o = 32; o; o >>= 1) s += __shfl_down(s, o);
    __shared__ float red[4];
    if ((threadIdx.x & 63) == 0) red[threadIdx.x >> 6] = s;
    __syncthreads();
    if (threadIdx.x == 0) {
        float t = red[0] + red[1] + red[2] + red[3];
        float x = -15.99f * (G[i * NH + j] - 0.0f);
        float sp = (x > 20.f) ? x : log1pf(expf(x));
        float wgt = 0.929f + (1.f - 0.929f) * sp;
        atomicAdd(out, wgt * t * (1.f / (float)NPAIRS));
    }
}

// ---------------------------------------------------------------- launcher
extern "C" void kernel_launch(void* const* d_in, const int* in_sizes, int n_in,
                              void* d_out, int out_size, void* d_ws, size_t ws_size,
                              hipStream_t stream) {
    const float* X = (const float*)d_in[0];
    const float* G = (const float*)d_in[1];
    float* out = (float*)d_out;
    char* ws = (char*)d_ws;

    float*         sum   = (float*)(ws + SUM_OFF);
    float*         sumsq = (float*)(ws + SUMSQ_OFF);
    float*         mu    = (float*)(ws + MU_OFF);
    float*         rinv  = (float*)(ws + RINV_OFF);
    float*         pairC = (float*)(ws + PC_OFF);
    unsigned char* Xt    = (unsigned char*)(ws + XT_OFF);

    hipMemsetAsync(ws + SUM_OFF, 0, 16384, stream);                     // sum+sumsq
    hipMemsetAsync(ws + PC_OFF, 0, (size_t)NPAIRS * DH * DH * 4, stream);
    hipMemsetAsync(d_out, 0, 4, stream);

    stats_transpose_kernel<<<dim3(16, 256), 256, 0, stream>>>(X, sum, sumsq, Xt);
    finalize_kernel<<<8, 256, 0, stream>>>(sum, sumsq, mu, rinv);
    gram_kernel<<<dim3(KCHUNKS, NPAIRS), 256, 0, stream>>>(Xt, pairC);
    pair_reduce_kernel<<<NPAIRS, 256, 0, stream>>>(pairC, G, mu, rinv, out);
}

// Round 2
// 290.911 us; speedup vs baseline: 1.0203x; 1.0203x over previous
//
#include <hip/hip_runtime.h>
#include <hip/hip_bf16.h>

// Problem constants
#define N_TOK   16384      // B*T
#define HDIM    2048       // H*d_h
#define NH      16
#define DH      128
#define NPAIRS  120
#define KCHUNKS 8
#define NKT     (N_TOK / 64)            // 256 k-tiles of 64 tokens
#define KT_PER_CHUNK (NKT / KCHUNKS)    // 32
#define PANEL_BYTES 8192                // 128 c-rows x 64 tokens x 1B (fp8)

// Workspace layout (bytes) — total ~41.5 MB
#define SUM_OFF    0u
#define SUMSQ_OFF  8192u
#define MU_OFF     16384u
#define RINV_OFF   24576u
#define PC_OFF     36864u                     // 120*128*128 f32 = 7,864,320 B
#define XT_OFF     7901184u                   // 2048*16384 fp8 = 33,554,432 B

typedef float     f32x4 __attribute__((ext_vector_type(4)));
typedef long long i64t;

// ---------------------------------------------------------------- fp8 e4m3 pack
#if __has_builtin(__builtin_amdgcn_cvt_pk_fp8_f32)
__device__ __forceinline__ unsigned pk4_fp8(float a, float b, float c, float d) {
    int w = __builtin_amdgcn_cvt_pk_fp8_f32(a, b, 0, false);   // bytes 0,1
    w = __builtin_amdgcn_cvt_pk_fp8_f32(c, d, w, true);        // bytes 2,3
    return (unsigned)w;
}
#else
__device__ __forceinline__ unsigned char f2e4m3_sw(float f) {
    unsigned u = __float_as_uint(f);
    unsigned s = (u >> 24) & 0x80u;
    unsigned a = u & 0x7fffffffu;
    if (a >= 0x43e00000u) return (unsigned char)(s | 0x7eu);   // clamp to 448
    if (a < 0x3c800000u) {                                     // |x| < 2^-6: subnormal
        float av = __uint_as_float(a);
        int q = (int)rintf(av * 512.0f);                       // units of 2^-9
        return (unsigned char)(s | (unsigned)q);               // q==8 -> 0x08 == 2^-6 normal
    }
    unsigned lsb = (a >> 20) & 1u;
    a += 0x7ffffu + lsb;                                       // RNE to 3 mantissa bits
    int e8 = (int)(a >> 23) - 120;                             // -127 + 7
    unsigned m = (a >> 20) & 7u;
    return (unsigned char)(s | ((unsigned)e8 << 3) | m);
}
__device__ __forceinline__ unsigned pk4_fp8(float a, float b, float c, float d) {
    return (unsigned)f2e4m3_sw(a) | ((unsigned)f2e4m3_sw(b) << 8) |
           ((unsigned)f2e4m3_sw(c) << 16) | ((unsigned)f2e4m3_sw(d) << 24);
}
#endif

// ---------------------------------------------------------------- pass 1: fused stats + panelized transpose + fp8
// Block = one 8 KB panel: head h, tokens n0..n0+63, all 128 head-dims.
// NEW: rows with (c>>3)&1 store their two 8B halves SWAPPED, so the gram
// kernel's LDS read swizzle can include r-bit-3 -> conflict-free ds_read_b64.
__global__ __launch_bounds__(256)
void stats_transpose_kernel(const float* __restrict__ X,
                            float* __restrict__ sum, float* __restrict__ sumsq,
                            unsigned char* __restrict__ Xt) {
    __shared__ float tile[64][129];               // stride 129
    __shared__ float sred[4][32][8];              // cross-wave stats partials
    const int h  = blockIdx.x;                    // 0..15
    const int by = blockIdx.y;                    // 0..255
    const int n0 = by * 64;
    const int tx = threadIdx.x;
    const int w  = tx >> 6, l = tx & 63;
    const int cq = tx & 31;                       // float4 index within 128-col slice
    const int rq0 = tx >> 5;                      // 0..7

    float4 s  = make_float4(0.f, 0.f, 0.f, 0.f);
    float4 ss = make_float4(0.f, 0.f, 0.f, 0.f);
    #pragma unroll
    for (int it = 0; it < 8; ++it) {
        int r = it * 8 + rq0;
        float4 x = *(const float4*)(X + (size_t)(n0 + r) * HDIM + h * DH + cq * 4);
        s.x += x.x; s.y += x.y; s.z += x.z; s.w += x.w;
        ss.x += x.x * x.x; ss.y += x.y * x.y; ss.z += x.z * x.z; ss.w += x.w * x.w;
        tile[r][cq * 4 + 0] = x.x; tile[r][cq * 4 + 1] = x.y;
        tile[r][cq * 4 + 2] = x.z; tile[r][cq * 4 + 3] = x.w;
    }
    s.x += __shfl_down(s.x, 32);  s.y += __shfl_down(s.y, 32);
    s.z += __shfl_down(s.z, 32);  s.w += __shfl_down(s.w, 32);
    ss.x += __shfl_down(ss.x, 32); ss.y += __shfl_down(ss.y, 32);
    ss.z += __shfl_down(ss.z, 32); ss.w += __shfl_down(ss.w, 32);
    if (l < 32) {
        sred[w][l][0] = s.x;  sred[w][l][1] = s.y;
        sred[w][l][2] = s.z;  sred[w][l][3] = s.w;
        sred[w][l][4] = ss.x; sred[w][l][5] = ss.y;
        sred[w][l][6] = ss.z; sred[w][l][7] = ss.w;
    }
    __syncthreads();
    if (tx < 32) {                                // wave 0 finishes stats
        float a0 = 0.f, a1 = 0.f, a2 = 0.f, a3 = 0.f;
        float b0 = 0.f, b1 = 0.f, b2 = 0.f, b3 = 0.f;
        #pragma unroll
        for (int w2 = 0; w2 < 4; ++w2) {
            a0 += sred[w2][tx][0]; a1 += sred[w2][tx][1];
            a2 += sred[w2][tx][2]; a3 += sred[w2][tx][3];
            b0 += sred[w2][tx][4]; b1 += sred[w2][tx][5];
            b2 += sred[w2][tx][6]; b3 += sred[w2][tx][7];
        }
        int c = h * DH + tx * 4;
        atomicAdd(&sum[c + 0], a0);  atomicAdd(&sum[c + 1], a1);
        atomicAdd(&sum[c + 2], a2);  atomicAdd(&sum[c + 3], a3);
        atomicAdd(&sumsq[c + 0], b0); atomicAdd(&sumsq[c + 1], b1);
        atomicAdd(&sumsq[c + 2], b2); atomicAdd(&sumsq[c + 3], b3);
    }
    // transpose write: 512 16B-chunks (one panel), contiguous per wave-instruction
    unsigned char* panel = Xt + ((size_t)h * NKT + by) * PANEL_BYTES;
    #pragma unroll
    for (int it = 0; it < 2; ++it) {
        int q = it * 256 + tx;
        int c = q >> 2, o = q & 3;                // chunk = (dim c, tokens 16o..16o+15)
        uint4 pk;
        pk.x = pk4_fp8(tile[o*16+ 0][c], tile[o*16+ 1][c], tile[o*16+ 2][c], tile[o*16+ 3][c]);
        pk.y = pk4_fp8(tile[o*16+ 4][c], tile[o*16+ 5][c], tile[o*16+ 6][c], tile[o*16+ 7][c]);
        pk.z = pk4_fp8(tile[o*16+ 8][c], tile[o*16+ 9][c], tile[o*16+10][c], tile[o*16+11][c]);
        pk.w = pk4_fp8(tile[o*16+12][c], tile[o*16+13][c], tile[o*16+14][c], tile[o*16+15][c]);
        // r-bit-3 half-swap: bakes the missing swizzle bit into the data so the
        // consumer's bank index depends on all 4 low row bits.
        uint4 outv = ((c >> 3) & 1) ? make_uint4(pk.z, pk.w, pk.x, pk.y) : pk;
        *(uint4*)(panel + c * 64 + o * 16) = outv;
    }
}

// ---------------------------------------------------------------- pass 3: pairwise raw Gram via fp8 MFMA
// 2-phase double-buffered pipeline. LDS layout: physical 8B unit p of row r
// holds logical unit p ^ (r&6) ^ ((r>>3)&1)  (chunk swizzle via global src
// address, bit-0 twist baked by pass 1's half-swap).
__device__ __forceinline__ void gload16(const void* gsrc, void* ldst) {
    __builtin_amdgcn_global_load_lds(
        (const __attribute__((address_space(1))) unsigned int*)gsrc,
        (__attribute__((address_space(3))) unsigned int*)ldst,
        16, 0, 0);
}

__global__ __launch_bounds__(256, 4)
void gram_kernel(const unsigned char* __restrict__ Xt, float* __restrict__ pairC) {
    const int kc = blockIdx.x;                    // K-chunk 0..7 -> XCD kc (linear%8)
    const int p  = blockIdx.y;                    // pair 0..119
    int i = 0, rem = p;
    while (rem >= NH - 1 - i) { rem -= NH - 1 - i; ++i; }
    const int j = i + 1 + rem;

    // [buf][A|B][8192] double-buffered staging: 32 KB -> 4 blocks/CU
    __shared__ alignas(16) unsigned char lds[2 * 2 * PANEL_BYTES];

    const int tx = threadIdx.x;
    const int w  = tx >> 6, l = tx & 63;
    const int wm = w >> 1, wn = w & 1;            // 2x2 wave grid over 128x128
    const int l15 = l & 15, quad = l >> 4;

    // Staging: panel = 128 rows x 4 chunks of 16B; chunk swizzle cc = cl ^ ((r>>1)&3)
    unsigned int goff0, goff1;
    {
        int r0 = tx >> 2, cl0 = tx & 3;
        goff0 = (unsigned int)(r0 * 64 + (cl0 ^ ((r0 >> 1) & 3)) * 16);
        int cfl = 256 + tx;
        int r1 = cfl >> 2, cl1 = cfl & 3;
        goff1 = (unsigned int)(r1 * 64 + (cl1 ^ ((r1 >> 1) & 3)) * 16);
    }
    const int lo0 = w * 1024;                     // wave-uniform LDS base, issue 0
    const int lo1 = 4096 + w * 1024;              // issue 1
    const char* Abase = (const char*)Xt + ((size_t)i * NKT + (size_t)kc * KT_PER_CHUNK) * PANEL_BYTES;
    const char* Bbase = (const char*)Xt + ((size_t)j * NKT + (size_t)kc * KT_PER_CHUNK) * PANEL_BYTES;

    f32x4 acc[4][4];
    #pragma unroll
    for (int mi = 0; mi < 4; ++mi)
        #pragma unroll
        for (int ni = 0; ni < 4; ++ni)
            acc[mi][ni] = (f32x4){0.f, 0.f, 0.f, 0.f};

    // Full row-dependent unit swizzle: rows within a frag differ by 16, so
    // r&6 == l15&6 and (r>>3)&1 == (l15>>3)&1. Bits disjoint -> OR.
    const int usw = (l15 & 6) | (l15 >> 3);

    // ---- prologue: stage tile 0 into buf 0, drain, barrier
    {
        const char* pa = Abase;
        const char* pb = Bbase;
        char* base = (char*)lds;
        gload16(pa + goff0, base + lo0);
        gload16(pa + goff1, base + lo1);
        gload16(pb + goff0, base + 8192 + lo0);
        gload16(pb + goff1, base + 8192 + lo1);
    }
    asm volatile("s_waitcnt vmcnt(0)\n\ts_barrier" ::: "memory");

    int cur = 0;
    for (int kt = 0; kt < KT_PER_CHUNK; ++kt) {
        // ---- issue next tile's loads into the other buffer (prefetch)
        if (kt + 1 < KT_PER_CHUNK) {
            const char* pa = Abase + (size_t)(kt + 1) * PANEL_BYTES;
            const char* pb = Bbase + (size_t)(kt + 1) * PANEL_BYTES;
            char* base = (char*)lds + (cur ^ 1) * (2 * PANEL_BYTES);
            gload16(pa + goff0, base + lo0);
            gload16(pa + goff1, base + lo1);
            gload16(pb + goff0, base + 8192 + lo0);
            gload16(pb + goff1, base + 8192 + lo1);
        }

        // ---- compute current buffer
        const unsigned char* la = lds + cur * (2 * PANEL_BYTES);
        const unsigned char* lb = la + PANEL_BYTES;
        #pragma unroll
        for (int kh = 0; kh < 2; ++kh) {          // two K=32 fp8 MFMA steps per 64-token tile
            const int u = (kh * 4 + quad) ^ usw;  // swizzled 8B unit
            i64t a[4], b[4];
            #pragma unroll
            for (int mi = 0; mi < 4; ++mi) {
                int r = wm * 64 + mi * 16 + l15;
                a[mi] = *(const i64t*)(la + r * 64 + u * 8);
            }
            #pragma unroll
            for (int ni = 0; ni < 4; ++ni) {
                int r = wn * 64 + ni * 16 + l15;
                b[ni] = *(const i64t*)(lb + r * 64 + u * 8);
            }
            #pragma unroll
            for (int mi = 0; mi < 4; ++mi)
                #pragma unroll
                for (int ni = 0; ni < 4; ++ni)
                    acc[mi][ni] = __builtin_amdgcn_mfma_f32_16x16x32_fp8_fp8(
                        a[mi], b[ni], acc[mi][ni], 0, 0, 0);
        }

        // ---- end-of-iter: wait prefetched loads (latency covered by MFMA above),
        //      ensure our LDS reads retired, then one barrier.
        if (kt + 1 < KT_PER_CHUNK) {
            asm volatile("s_waitcnt vmcnt(0) lgkmcnt(0)\n\ts_barrier" ::: "memory");
        }
        cur ^= 1;
    }

    // Epilogue: partial raw Gram -> atomic accumulate (KCHUNKS contenders/address)
    float* pc = pairC + (size_t)p * (DH * DH);
    #pragma unroll
    for (int mi = 0; mi < 4; ++mi)
        #pragma unroll
        for (int ni = 0; ni < 4; ++ni)
            #pragma unroll
            for (int r = 0; r < 4; ++r) {
                int row = wm * 64 + mi * 16 + quad * 4 + r;  // d (head-i dim)
                int col = wn * 64 + ni * 16 + l15;           // e (head-j dim)
                atomicAdd(&pc[row * DH + col], acc[mi][ni][r]);
            }
}

// ---------------------------------------------------------------- pass 4: per-pair loss + final accumulate
// (finalize fused: mu/rinv computed inline from sum/sumsq — one fewer dispatch)
__global__ void pair_reduce_kernel(const float* __restrict__ pairC, const float* __restrict__ G,
                                   const float* __restrict__ sum, const float* __restrict__ sumsq,
                                   float* __restrict__ out) {
    int p = blockIdx.x;
    int i = 0, rem = p;
    while (rem >= NH - 1 - i) { rem -= NH - 1 - i; ++i; }
    int j = i + 1 + rem;
    __shared__ float smui[DH], smuj[DH], sri[DH], srj[DH];
    {
        int t = threadIdx.x;
        int head = (t < DH) ? i : j;
        int d = t & (DH - 1);
        int c = head * DH + d;
        float m = sum[c] * (1.f / (float)N_TOK);
        float var = (sumsq[c] - (float)N_TOK * m * m) * (1.f / (float)(N_TOK - 1));
        var = fmaxf(var, 0.f);
        float r = 1.f / (sqrtf(var) + 1e-8f);
        if (t < DH) { smui[d] = m; sri[d] = r; }
        else        { smuj[d] = m; srj[d] = r; }
    }
    __syncthreads();
    const float invN = 1.f / (float)N_TOK;
    const float* pc = pairC + (size_t)p * (DH * DH);
    float s = 0.f;
    for (int idx = threadIdx.x; idx < DH * DH; idx += 256) {
        int d = idx >> 7, e = idx & 127;
        float cn = (pc[idx] * invN - smui[d] * smuj[e]) * sri[d] * srj[e];
        float diff = cn - ((d == e) ? 1.f : 0.f);
        s += diff * diff;
    }
    for (int o = 32; o; o >>= 1) s += __shfl_down(s, o);
    __shared__ float red[4];
    if ((threadIdx.x & 63) == 0) red[threadIdx.x >> 6] = s;
    __syncthreads();
    if (threadIdx.x == 0) {
        float t = red[0] + red[1] + red[2] + red[3];
        float x = -15.99f * (G[i * NH + j] - 0.0f);
        float sp = (x > 20.f) ? x : log1pf(expf(x));
        float wgt = 0.929f + (1.f - 0.929f) * sp;
        atomicAdd(out, wgt * t * (1.f / (float)NPAIRS));
    }
}

// ---------------------------------------------------------------- launcher
extern "C" void kernel_launch(void* const* d_in, const int* in_sizes, int n_in,
                              void* d_out, int out_size, void* d_ws, size_t ws_size,
                              hipStream_t stream) {
    const float* X = (const float*)d_in[0];
    const float* G = (const float*)d_in[1];
    float* out = (float*)d_out;
    char* ws = (char*)d_ws;

    float*         sum   = (float*)(ws + SUM_OFF);
    float*         sumsq = (float*)(ws + SUMSQ_OFF);
    float*         pairC = (float*)(ws + PC_OFF);
    unsigned char* Xt    = (unsigned char*)(ws + XT_OFF);

    hipMemsetAsync(ws + SUM_OFF, 0, 16384, stream);                     // sum+sumsq
    hipMemsetAsync(ws + PC_OFF, 0, (size_t)NPAIRS * DH * DH * 4, stream);
    hipMemsetAsync(d_out, 0, 4, stream);

    stats_transpose_kernel<<<dim3(16, 256), 256, 0, stream>>>(X, sum, sumsq, Xt);
    gram_kernel<<<dim3(KCHUNKS, NPAIRS), 256, 0, stream>>>(Xt, pairC);
    pair_reduce_kernel<<<NPAIRS, 256, 0, stream>>>(pairC, G, sum, sumsq, out);
}